// Round 6
// baseline (3830.860 us; speedup 1.0000x reference)
//
#include <hip/hip_runtime.h>
#include <hip/hip_bf16.h>
#include <cstdint>
#include <cstddef>

typedef short bf16x8 __attribute__((ext_vector_type(8)));
typedef float f32x4 __attribute__((ext_vector_type(4)));
typedef int   i32x4 __attribute__((ext_vector_type(4)));

#define DEV static __device__ __forceinline__

DEV unsigned short f2bf(float x){
  union{float f; unsigned int u;} v; v.f = x;
  unsigned int r = (v.u + 0x7FFFu + ((v.u>>16)&1u)) >> 16;
  return (unsigned short)r;
}
DEV float bf2f(unsigned short h){
  union{unsigned int u; float f;} v; v.u = ((unsigned int)h)<<16;
  return v.f;
}
// unpack bf16 half of a dword: hi=0 -> low u16, hi=1 -> high u16
DEV float bfsel(int dw, int hi){
  union{unsigned int u; float f;} v;
  v.u = hi ? ((unsigned int)dw & 0xFFFF0000u) : ((unsigned int)dw << 16);
  return v.f;
}
// fast gates: v_exp_f32 + v_rcp_f32
DEV float sigm_f(float x){ return __builtin_amdgcn_rcpf(1.0f + __expf(-x)); }
DEV float tanh_f(float x){ return 2.0f*__builtin_amdgcn_rcpf(1.0f + __expf(-2.0f*x)) - 1.0f; }

// ---------------- prep kernels ----------------
__global__ void k_f2bf(const float* __restrict__ src, unsigned short* __restrict__ dst, int n){
  int i = blockIdx.x*256 + threadIdx.x;
  if(i<n) dst[i] = f2bf(src[i]);
}

__global__ void k_transpose(const float* __restrict__ in, float* __restrict__ out, int R, int C){
  int i = blockIdx.x*256 + threadIdx.x;
  if(i < R*C){ int r = i/C, c = i - r*C; out[(size_t)c*R + r] = in[i]; }
}

__global__ void k_attw1(const float* __restrict__ w1, unsigned short* __restrict__ dst){
  int i = blockIdx.x*256 + threadIdx.x;  // 128*1824
  if(i < 128*1824){
    int r = i/1824, cc = i - r*1824;
    float v = (r<100 && cc<1794)? w1[r*1794 + cc] : 0.0f;
    dst[i] = f2bf(v);
  }
}

__global__ void k_attwT(const float* __restrict__ aw, unsigned short* __restrict__ dst){
  int i = blockIdx.x*256 + threadIdx.x;  // out[n*256+k] = aw[k*256+n]
  if(i<65536){ int n = i>>8, k = i&255; dst[i] = f2bf(aw[k*256 + n]); }
}

__global__ void k_b1pad(const float* __restrict__ b1, float* __restrict__ dst){
  int i = threadIdx.x; if(i<128) dst[i] = (i<100)? b1[i] : 0.0f;
}

__global__ void k_copy(const float* __restrict__ s, float* __restrict__ d, int n){
  int i = blockIdx.x*256+threadIdx.x; if(i<n) d[i]=s[i];
}

// ---------------- generic bf16 MFMA GEMM: C(M,N) = A(M,K) @ Bt(N,K)^T ----------------
__global__ __launch_bounds__(256) void k_gemm_bf16(
    const unsigned short* __restrict__ A, const unsigned short* __restrict__ Bt,
    int K, const float* __restrict__ bias, int act,
    float* __restrict__ outf, unsigned short* __restrict__ outbf, int ldc)
{
  int lane = threadIdx.x & 63, wave = threadIdx.x >> 6;
  int m_base = blockIdx.x*64 + (wave>>1)*32;
  int n_base = blockIdx.y*64 + (wave&1)*32;
  int cl = lane & 15, q4 = lane >> 4;
  f32x4 acc00={0.f,0.f,0.f,0.f}, acc01=acc00, acc10=acc00, acc11=acc00;
  const int kf_n = K >> 5;
  for(int kf=0; kf<kf_n; kf++){
    int ko = kf*32 + q4*8;
    bf16x8 a0 = *(const bf16x8*)(A + (size_t)(m_base+cl)*K + ko);
    bf16x8 a1 = *(const bf16x8*)(A + (size_t)(m_base+16+cl)*K + ko);
    bf16x8 b0 = *(const bf16x8*)(Bt + (size_t)(n_base+cl)*K + ko);
    bf16x8 b1 = *(const bf16x8*)(Bt + (size_t)(n_base+16+cl)*K + ko);
    acc00 = __builtin_amdgcn_mfma_f32_16x16x32_bf16(a0,b0,acc00,0,0,0);
    acc01 = __builtin_amdgcn_mfma_f32_16x16x32_bf16(a0,b1,acc01,0,0,0);
    acc10 = __builtin_amdgcn_mfma_f32_16x16x32_bf16(a1,b0,acc10,0,0,0);
    acc11 = __builtin_amdgcn_mfma_f32_16x16x32_bf16(a1,b1,acc11,0,0,0);
  }
  #pragma unroll
  for(int mt=0; mt<2; mt++){
    #pragma unroll
    for(int nt=0; nt<2; nt++){
      f32x4 av = (mt==0)? (nt==0?acc00:acc01) : (nt==0?acc10:acc11);
      int col = n_base + nt*16 + cl;
      float bv = bias? bias[col] : 0.0f;
      #pragma unroll
      for(int r=0;r<4;r++){
        int row = m_base + mt*16 + q4*4 + r;
        float v = av[r] + bv;
        if(act) v = tanh_f(v);
        if(outbf) outbf[(size_t)row*ldc + col] = f2bf(v);
        else      outf [(size_t)row*ldc + col] = v;
      }
    }
  }
}

// ---------------- gi GEMM with lane-packed scatter epilogue ----------------
// gi = x @ w_ih^T. r/z gates: f32, biases b_ih+b_hh FOLDED (phase B = 1 add).
// n gate: bf16 with b_ih folded (b_hh_n must stay inside the r* term).
// Lane-packed: rz idx = L*16 + g*8 + s*4 + r ; n idx = L*8 + s*4 + r,
// L = (((t*2 + blk)*8 + w)*64 + lane). A rows are b*steps + t (steps = 1<<ss).
__global__ __launch_bounds__(256) void k_gemm_gi(
    const unsigned short* __restrict__ A, const unsigned short* __restrict__ Bt,
    const float* __restrict__ bih, const float* __restrict__ bhh,
    float* __restrict__ rz_out, unsigned short* __restrict__ n_out, int ss)
{
  int lane = threadIdx.x & 63, wave = threadIdx.x >> 6;
  int m_base = blockIdx.x*64 + (wave>>1)*32;
  int n_base = blockIdx.y*64 + (wave&1)*32;
  int cl = lane & 15, q4 = lane >> 4;
  f32x4 acc00={0.f,0.f,0.f,0.f}, acc01=acc00, acc10=acc00, acc11=acc00;
  for(int kf=0; kf<4; kf++){   // K = 128
    int ko = kf*32 + q4*8;
    bf16x8 a0 = *(const bf16x8*)(A + (size_t)(m_base+cl)*128 + ko);
    bf16x8 a1 = *(const bf16x8*)(A + (size_t)(m_base+16+cl)*128 + ko);
    bf16x8 b0 = *(const bf16x8*)(Bt + (size_t)(n_base+cl)*128 + ko);
    bf16x8 b1 = *(const bf16x8*)(Bt + (size_t)(n_base+16+cl)*128 + ko);
    acc00 = __builtin_amdgcn_mfma_f32_16x16x32_bf16(a0,b0,acc00,0,0,0);
    acc01 = __builtin_amdgcn_mfma_f32_16x16x32_bf16(a0,b1,acc01,0,0,0);
    acc10 = __builtin_amdgcn_mfma_f32_16x16x32_bf16(a1,b0,acc10,0,0,0);
    acc11 = __builtin_amdgcn_mfma_f32_16x16x32_bf16(a1,b1,acc11,0,0,0);
  }
  const int tmask = (1<<ss) - 1;
  #pragma unroll
  for(int mt=0; mt<2; mt++){
    #pragma unroll
    for(int nt=0; nt<2; nt++){
      f32x4 av = (mt==0)? (nt==0?acc00:acc01) : (nt==0?acc10:acc11);
      int col = n_base + nt*16 + cl;
      float bi = bih[col];
      int g = col >> 8, rem = col & 255;      // g uniform per (grid,wave,nt)
      int w = rem >> 5, s = (rem>>4)&1, cl2 = rem & 15;
      float bh = (g<2)? bhh[col] : 0.0f;
      #pragma unroll
      for(int r=0;r<4;r++){
        int arow = m_base + mt*16 + q4*4 + r;
        int t = arow & tmask, b = arow >> ss;
        int blk = b >> 4, brow = b & 15;
        int lane2 = (brow>>2)*16 + cl2, rc = brow & 3;
        size_t L = ((((size_t)t*2 + blk)*8 + w)*64 + lane2);
        if(g < 2) rz_out[L*16 + g*8 + s*4 + rc] = av[r] + bi + bh;
        else      n_out [L*8  + s*4 + rc]       = f2bf(av[r] + bi);
      }
    }
  }
}

// ---------------- GRU recurrence ----------------
// 4 blocks (2 context, 2 query), 16 batch rows each, 8 waves.
// Gate-local tiling (wave w owns cols [32w,32w+32) of r/z/n); W register-resident.
// h double-buffered in LDS -> one __syncthreads per step (r4 skeleton; r5's
// lgkm-only asm barrier + cross-step prefetch REGRESSED 18% -- reverted).
// gi: r/z as f32 bias-folded (no unpack, one add), n as bf16; loaded at step top,
// consumed in phase B (phase-A MFMA cover, ~r4 structure).
__global__ __launch_bounds__(512,1) void k_gru_rec(
    const unsigned short* __restrict__ whh_c, const unsigned short* __restrict__ whh_q,
    const float* __restrict__ rz_c, const unsigned short* __restrict__ n_c,
    const float* __restrict__ rz_q, const unsigned short* __restrict__ n_q,
    const float* __restrict__ bhh_c, const float* __restrict__ bhh_q,
    const float* __restrict__ h0_c,  const float* __restrict__ h0_q,
    float* __restrict__ c_out, float* __restrict__ q_hT)
{
  __shared__ unsigned short hb0[16*264];   // double-buffered h (row stride 264 u16)
  __shared__ unsigned short hb1[16*264];

  const int blk = blockIdx.x;
  const bool isq = blk >= 2;
  const int cls = isq? blk-2 : blk;        // block index within class (0/1)
  const int b0 = cls * 16;
  const unsigned short* W  = isq? whh_q : whh_c;
  const float* RZ = isq? rz_q : rz_c;
  const unsigned short* NG = isq? n_q : n_c;
  const float* bhh = isq? bhh_q : bhh_c;
  const float* h0  = isq? h0_q  : h0_c;
  const int steps  = isq? 32 : 1024;

  const int tid = threadIdx.x;
  const int lane = tid & 63, wave = tid >> 6;
  const int cl = lane & 15, q4 = lane >> 4;

  // B-fragments: [gate][subtile][kfrag], col = g*256 + wave*32 + s*16 + cl
  bf16x8 Bf[3][2][8];
  #pragma unroll
  for(int g=0; g<3; g++)
    #pragma unroll
    for(int s=0; s<2; s++){
      const unsigned short* wrow = W + (size_t)(g*256 + wave*32 + s*16 + cl)*256;
      #pragma unroll
      for(int kf=0; kf<8; kf++)
        Bf[g][s][kf] = *(const bf16x8*)(wrow + kf*32 + q4*8);
    }

  // n-gate hidden bias for owned cols (r/z biases folded into rz gi)
  float bN[2];
  #pragma unroll
  for(int s=0; s<2; s++){
    const int col = wave*32 + s*16 + cl;
    bN[s] = bhh[512+col];
  }

  // h in registers: lane owns (row=q4*4+r, col=wave*32+s*16+cl)
  float hreg[2][4];
  #pragma unroll
  for(int s=0; s<2; s++){
    const int col = wave*32 + s*16 + cl;
    #pragma unroll
    for(int r=0; r<4; r++){
      const int row = q4*4 + r;
      float v = h0[(size_t)(b0+row)*256 + col];
      hreg[s][r] = v;
      hb0[row*264 + col] = f2bf(v);
    }
  }
  __syncthreads();

  unsigned short* hb_rd = hb0;
  unsigned short* hb_wr = hb1;

  // per-lane gi bases
  const float* rz_lane = RZ + (((size_t)cls*8 + wave)*64 + lane)*16;
  const unsigned short* n_lane = NG + (((size_t)cls*8 + wave)*64 + lane)*8;
  const size_t rz_tstride = (size_t)2*8*64*16;   // f32 per t
  const size_t n_tstride  = (size_t)2*8*64*8;    // u16 per t

  for(int t=0; t<steps; t++){
    // gi(t): 4x f32x4 (r,z bias-folded) + 1x dwordx4 (n bf16); consumed in phase B
    const float* rzp = rz_lane + (size_t)t*rz_tstride;
    f32x4 Gr0 = *(const f32x4*)(rzp);        // r gate, s=0 (r0..r3)
    f32x4 Gr1 = *(const f32x4*)(rzp + 4);    // r gate, s=1
    f32x4 Gz0 = *(const f32x4*)(rzp + 8);    // z gate, s=0
    f32x4 Gz1 = *(const f32x4*)(rzp + 12);   // z gate, s=1
    i32x4 Nw  = *(const i32x4*)(n_lane + (size_t)t*n_tstride);

    // deferred c_out store of h(t-1): overlaps with MFMA phase
    if(!isq && t>0){
      #pragma unroll
      for(int s=0; s<2; s++){
        const int col = wave*32 + s*16 + cl;
        #pragma unroll
        for(int r=0; r<4; r++)
          c_out[((size_t)(b0+q4*4+r)*1024 + (t-1))*256 + col] = hreg[s][r];
      }
    }

    // phase A: gates = h @ W^T  (48 MFMAs/wave)
    f32x4 acc[3][2];
    #pragma unroll
    for(int g=0; g<3; g++)
      #pragma unroll
      for(int s=0; s<2; s++){ f32x4 z={0.f,0.f,0.f,0.f}; acc[g][s]=z; }
    #pragma unroll
    for(int kf=0; kf<8; kf++){
      bf16x8 a = *(const bf16x8*)&hb_rd[cl*264 + kf*32 + q4*8];
      #pragma unroll
      for(int g=0; g<3; g++)
        #pragma unroll
        for(int s=0; s<2; s++)
          acc[g][s] = __builtin_amdgcn_mfma_f32_16x16x32_bf16(a, Bf[g][s][kf], acc[g][s], 0,0,0);
    }

    // phase B: in-register GRU update (writes OTHER h buffer)
    #pragma unroll
    for(int s=0; s<2; s++){
      const int col = wave*32 + s*16 + cl;
      float x4[4];
      #pragma unroll
      for(int r=0; r<4; r++){
        const int k = s*4 + r;
        float rr = sigm_f((s? Gr1[r] : Gr0[r]) + acc[0][s][r]);
        float zz = sigm_f((s? Gz1[r] : Gz0[r]) + acc[1][s][r]);
        float gin = bfsel(Nw[k>>1], k&1);
        float nn = tanh_f(gin + rr*(acc[2][s][r] + bN[s]));
        float x  = nn + zz*(hreg[s][r] - nn);
        hreg[s][r] = x;
        x4[r] = x;
      }
      // packed bf16 writeback: v_cvt_pk_bf16_f32 (2 values/instr)
      #pragma unroll
      for(int p=0; p<2; p++){
        __hip_bfloat162 bb = __float22bfloat162_rn(make_float2(x4[2*p], x4[2*p+1]));
        union{ __hip_bfloat162 b; unsigned int u; } cvt; cvt.b = bb;
        const int row = q4*4 + 2*p;
        hb_wr[row*264 + col]     = (unsigned short)(cvt.u & 0xFFFFu);
        hb_wr[(row+1)*264 + col] = (unsigned short)(cvt.u >> 16);
      }
    }
    __syncthreads();   // hb_wr complete -> next step's phase A may read it
    unsigned short* tmp = hb_rd; hb_rd = hb_wr; hb_wr = tmp;
  }

  // final stores from hreg
  #pragma unroll
  for(int s=0; s<2; s++){
    const int col = wave*32 + s*16 + cl;
    #pragma unroll
    for(int r=0; r<4; r++){
      const int row = q4*4 + r;
      if(!isq) c_out[((size_t)(b0+row)*1024 + (steps-1))*256 + col] = hreg[s][r];
      else     q_hT[(size_t)(b0+row)*256 + col] = hreg[s][r];
    }
  }
}

// ---------------- attention helpers ----------------
__global__ void k_gather(const float* __restrict__ c_out, const int* __restrict__ c_index,
                         float* __restrict__ c_sel, unsigned short* __restrict__ c_sel_bf){
  int row = blockIdx.x;                 // 0..4095 = b*128+s
  int b = row >> 7, s = row & 127;
  int idx = c_index[b*128 + s];
  float v = c_out[((size_t)b*1024 + idx)*256 + threadIdx.x];
  c_sel   [(size_t)row*256 + threadIdx.x] = v;
  c_sel_bf[(size_t)row*256 + threadIdx.x] = f2bf(v);
}

__global__ void k_feats(const float* __restrict__ c_sel, const float* __restrict__ cw,
                        const float* __restrict__ m_, const float* __restrict__ qh,
                        unsigned short* __restrict__ feats){
  int row = blockIdx.x, tid = threadIdx.x;
  int b = row >> 7;
  float cs  = c_sel[(size_t)row*256 + tid];
  float mj  = m_[b*256 + tid];
  float qj  = qh[b*256 + tid];
  float cwj = cw[(size_t)row*256 + tid];
  float dq = cwj*qj, dm = cwj*mj;
  #pragma unroll
  for(int o=32;o>0;o>>=1){ dq += __shfl_down(dq,o); dm += __shfl_down(dm,o); }
  __shared__ float rq[4], rm[4];
  int lane = tid&63, wave=tid>>6;
  if(lane==0){ rq[wave]=dq; rm[wave]=dm; }
  __syncthreads();
  unsigned short* fr = feats + (size_t)row*1824;
  fr[tid]      = f2bf(cs);
  fr[256+tid]  = f2bf(mj);
  fr[512+tid]  = f2bf(qj);
  fr[768+tid]  = f2bf(cs*qj);
  fr[1024+tid] = f2bf(cs*mj);
  fr[1280+tid] = f2bf(fabsf(cs-qj));
  fr[1536+tid] = f2bf(fabsf(cs-mj));
  if(tid==0){
    float DQ = rq[0]+rq[1]+rq[2]+rq[3];
    float DM = rm[0]+rm[1]+rm[2]+rm[3];
    fr[1792]=f2bf(DQ); fr[1793]=f2bf(DM);
  }
  if(tid<30) fr[1794+tid]=0;   // zero K-pad
}

__global__ void k_scores(const float* __restrict__ h1, const float* __restrict__ w2,
                         const float* __restrict__ b2, float* __restrict__ scores){
  int row = blockIdx.x*4 + (threadIdx.x>>6);
  int lane = threadIdx.x & 63;
  float v = 0.0f;
  if(lane < 100)    v += h1[(size_t)row*128 + lane]*w2[lane];
  if(lane+64 < 100) v += h1[(size_t)row*128 + lane+64]*w2[lane+64];
  #pragma unroll
  for(int o=32;o>0;o>>=1) v += __shfl_down(v,o);
  if(lane==0) scores[row] = v + b2[0];
}

__global__ void k_softmax_e(const float* __restrict__ scores, const int* __restrict__ len_c,
                            const float* __restrict__ c_sel, float* __restrict__ out_att,
                            float* __restrict__ e){
  __shared__ float red[256];
  __shared__ float p[128];
  int b = blockIdx.x, tid = threadIdx.x;
  int L = len_c[b];
  float s = -1e30f;
  if(tid<128 && tid<L) s = scores[b*128+tid];
  red[tid]=s; __syncthreads();
  for(int o=128;o>0;o>>=1){ if(tid<o) red[tid]=fmaxf(red[tid],red[tid+o]); __syncthreads(); }
  float mx = red[0]; __syncthreads();
  float ex = (tid<128 && tid<L)? __expf(s-mx) : 0.0f;
  red[tid]=ex; __syncthreads();
  for(int o=128;o>0;o>>=1){ if(tid<o) red[tid]+=red[tid+o]; __syncthreads(); }
  float inv = 1.0f/red[0];
  if(tid<128){ float pv = ex*inv; p[tid]=pv; out_att[b*128+tid]=pv; }
  __syncthreads();
  float acc = 0.0f;
  for(int si=0; si<128; si++) acc += p[si]*c_sel[((size_t)b*128+si)*256 + tid];
  e[b*256+tid] = acc;
}

// ---------------- small fp32 GRU cell (mem/ans updates), x = [x1 || x2] ----------------
__global__ void k_gru_cell(const float* __restrict__ x1, int len1,
                           const float* __restrict__ x2, int len2,
                           const float* __restrict__ hprev,
                           const float* __restrict__ wihT, const float* __restrict__ whhT,
                           const float* __restrict__ bih, const float* __restrict__ bhh,
                           float* __restrict__ hout){
  __shared__ float xs[2304];
  __shared__ float hs[256];
  int m = blockIdx.x, tid = threadIdx.x;
  int Kx = len1 + len2;
  for(int i=tid;i<len1;i+=256) xs[i] = x1[(size_t)m*len1 + i];
  for(int i=tid;i<len2;i+=256) xs[len1+i] = x2[(size_t)m*len2 + i];
  hs[tid] = hprev[m*256 + tid];
  __syncthreads();
  float ar=0, az=0, an=0;
  for(int k=0;k<Kx;k++){
    float xv = xs[k];
    const float* wr = wihT + (size_t)k*768;
    ar += xv*wr[tid]; az += xv*wr[256+tid]; an += xv*wr[512+tid];
  }
  float gr=0, gz=0, gn=0;
  for(int k=0;k<256;k++){
    float hv = hs[k];
    const float* wr = whhT + (size_t)k*768;
    gr += hv*wr[tid]; gz += hv*wr[256+tid]; gn += hv*wr[512+tid];
  }
  float rr = sigm_f(ar + bih[tid]     + gr + bhh[tid]);
  float zz = sigm_f(az + bih[256+tid] + gz + bhh[256+tid]);
  float nn = tanh_f(an + bih[512+tid] + rr*(gn + bhh[512+tid]));
  hout[m*256+tid] = (1.0f-zz)*nn + zz*hs[tid];
}

// ---------------- answer head ----------------
__global__ void k_logits(const float* __restrict__ msq, const float* __restrict__ out_wT,
                         const float* __restrict__ out_b, float* __restrict__ ylin){
  int i = blockIdx.x*256 + threadIdx.x;
  if(i >= 32*2000) return;
  int mrow = i/2000, n = i - mrow*2000;
  float acc = out_b[n];
  const float* mr = msq + mrow*256;
  for(int k=0;k<256;k++) acc += mr[k]*out_wT[(size_t)k*2000 + n];
  ylin[i] = acc;
}

__global__ void k_softmax_o(const float* __restrict__ x, float* __restrict__ y){
  __shared__ float red[256];
  int b = blockIdx.x, tid = threadIdx.x;
  const float* xr = x + (size_t)b*2000;
  float mx = -1e30f;
  for(int i=tid;i<2000;i+=256) mx = fmaxf(mx, xr[i]);
  red[tid]=mx; __syncthreads();
  for(int o=128;o>0;o>>=1){ if(tid<o) red[tid]=fmaxf(red[tid],red[tid+o]); __syncthreads(); }
  mx = red[0]; __syncthreads();
  float sum=0.0f;
  for(int i=tid;i<2000;i+=256) sum += __expf(xr[i]-mx);
  red[tid]=sum; __syncthreads();
  for(int o=128;o>0;o>>=1){ if(tid<o) red[tid]+=red[tid+o]; __syncthreads(); }
  float inv = 1.0f/red[0];
  for(int i=tid;i<2000;i+=256) y[(size_t)b*2000+i] = __expf(xr[i]-mx)*inv;
}

// ---------------- launch ----------------
extern "C" void kernel_launch(void* const* d_in, const int* in_sizes, int n_in,
                              void* d_out, int out_size, void* d_ws, size_t ws_size,
                              hipStream_t stream)
{
  const float* c        = (const float*)d_in[0];
  const float* q        = (const float*)d_in[1];
  const float* i_state  = (const float*)d_in[2];
  const float* q_state  = (const float*)d_in[3];
  const float* in_w_ih  = (const float*)d_in[4];
  const float* in_w_hh  = (const float*)d_in[5];
  const float* in_b_ih  = (const float*)d_in[6];
  const float* in_b_hh  = (const float*)d_in[7];
  const float* qe_w_ih  = (const float*)d_in[8];
  const float* qe_w_hh  = (const float*)d_in[9];
  const float* qe_b_ih  = (const float*)d_in[10];
  const float* qe_b_hh  = (const float*)d_in[11];
  const float* att_weight = (const float*)d_in[12];
  const float* att_w1   = (const float*)d_in[13];
  const float* att_b1   = (const float*)d_in[14];
  const float* att_w2   = (const float*)d_in[15];
  const float* att_b2   = (const float*)d_in[16];
  const float* mem_w_ih = (const float*)d_in[17];
  const float* mem_w_hh = (const float*)d_in[18];
  const float* mem_b_ih = (const float*)d_in[19];
  const float* mem_b_hh = (const float*)d_in[20];
  const float* out_w    = (const float*)d_in[21];
  const float* out_b    = (const float*)d_in[22];
  const float* ans_w_ih = (const float*)d_in[23];
  const float* ans_w_hh = (const float*)d_in[24];
  const float* ans_b_ih = (const float*)d_in[25];
  const float* ans_b_hh = (const float*)d_in[26];
  const int*   c_index  = (const int*)d_in[27];
  const int*   len_c    = (const int*)d_in[28];
  float* outp = (float*)d_out;   // [0,64000) y ; [64000,76288) att (3,32,128)

  char* wp = (char*)d_ws;
  auto take = [&](size_t nbytes)->char*{
    char* p = wp; wp += (nbytes + 255) & ~(size_t)255; return p;
  };
  unsigned short* c_bf      = (unsigned short*)take((size_t)32*1024*128*2);
  unsigned short* q_bf      = (unsigned short*)take((size_t)32*32*128*2);
  unsigned short* wih_in_bf = (unsigned short*)take(768*128*2);
  unsigned short* wih_qe_bf = (unsigned short*)take(768*128*2);
  unsigned short* whh_in_bf = (unsigned short*)take(768*256*2);
  unsigned short* whh_qe_bf = (unsigned short*)take(768*256*2);
  unsigned short* attwT_bf  = (unsigned short*)take(256*256*2);
  unsigned short* attw1_bf  = (unsigned short*)take(128*1824*2);
  float* b1pad              = (float*)take(128*4);
  float* out_wT             = (float*)take((size_t)256*2000*4);
  float* mem_wihT           = (float*)take(256*768*4);
  float* mem_whhT           = (float*)take(256*768*4);
  float* ans_wihT           = (float*)take((size_t)2256*768*4);
  float* ans_whhT           = (float*)take(256*768*4);

  // ---- UNION region: gi buffers (dead after k_gru_rec) alias the attention
  //      temporaries (born after k_gru_rec). Keeps total ws ~flat despite f32 gi.
  char* region = take((size_t)86507520);
  float*          gi_rz_c = (float*)(region);                       // 67,108,864 B
  unsigned short* gi_n_c  = (unsigned short*)(region + 67108864);   // 16,777,216 B
  float*          gi_rz_q = (float*)(region + 83886080);            //  2,097,152 B
  unsigned short* gi_n_q  = (unsigned short*)(region + 85983232);   //    524,288 B
  // aliased (post-recurrence lifetimes):
  float*          c_sel    = (float*)(region);                      //  4,194,304 B
  unsigned short* c_sel_bf = (unsigned short*)(region + 4194304);   //  2,097,152 B
  float*          cw       = (float*)(region + 6291456);            //  4,194,304 B
  unsigned short* feats_bf = (unsigned short*)(region + 10485760);  // 14,942,208 B
  float*          h1       = (float*)(region + 25427968);           //  2,097,152 B
  float*          scores   = (float*)(region + 27525120);           //     16,384 B

  float* c_out              = (float*)take((size_t)32*1024*256*4);
  float* q_hT               = (float*)take(32*256*4);
  float* e_buf              = (float*)take(32*256*4);
  float* m_buf              = (float*)take(32*256*4);
  float* msq                = (float*)take(32*256*4);
  float* ylin               = (float*)take((size_t)32*2000*4);
  float* ybuf               = (float*)take((size_t)32*2000*4);

  // ---- prep / conversions ----
  k_f2bf<<<16384,256,0,stream>>>(c, c_bf, 32*1024*128);
  k_f2bf<<<512,256,0,stream>>>(q, q_bf, 32*32*128);
  k_f2bf<<<384,256,0,stream>>>(in_w_ih, wih_in_bf, 768*128);
  k_f2bf<<<384,256,0,stream>>>(qe_w_ih, wih_qe_bf, 768*128);
  k_f2bf<<<768,256,0,stream>>>(in_w_hh, whh_in_bf, 768*256);
  k_f2bf<<<768,256,0,stream>>>(qe_w_hh, whh_qe_bf, 768*256);
  k_attwT<<<256,256,0,stream>>>(att_weight, attwT_bf);
  k_attw1<<<912,256,0,stream>>>(att_w1, attw1_bf);
  k_b1pad<<<1,128,0,stream>>>(att_b1, b1pad);
  k_transpose<<<2000,256,0,stream>>>(out_w, out_wT, 2000, 256);
  k_transpose<<<768,256,0,stream>>>(mem_w_ih, mem_wihT, 768, 256);
  k_transpose<<<768,256,0,stream>>>(mem_w_hh, mem_whhT, 768, 256);
  k_transpose<<<6768,256,0,stream>>>(ans_w_ih, ans_wihT, 768, 2256);
  k_transpose<<<768,256,0,stream>>>(ans_w_hh, ans_whhT, 768, 256);

  // ---- time-parallel input projections, lane-packed + bias-folded ----
  k_gemm_gi<<<dim3(512,12),256,0,stream>>>(c_bf, wih_in_bf, in_b_ih, in_b_hh, gi_rz_c, gi_n_c, 10);
  k_gemm_gi<<<dim3(16,12),256,0,stream>>>(q_bf, wih_qe_bf, qe_b_ih, qe_b_hh, gi_rz_q, gi_n_q, 5);

  // ---- sequential GRU recurrences (context 1024 steps + query 32 steps) ----
  k_gru_rec<<<4,512,0,stream>>>(whh_in_bf, whh_qe_bf, gi_rz_c, gi_n_c, gi_rz_q, gi_n_q,
                                in_b_hh, qe_b_hh, i_state, q_state, c_out, q_hT);

  // ---- attention setup (gi region now dead; attention aliases begin) ----
  k_gather<<<4096,256,0,stream>>>(c_out, c_index, c_sel, c_sel_bf);
  k_gemm_bf16<<<dim3(64,4),256,0,stream>>>(c_sel_bf, attwT_bf, 256, nullptr, 0, cw, nullptr, 256);
  k_copy<<<32,256,0,stream>>>(q_hT, m_buf, 32*256);

  // ---- 3 episodic memory iterations ----
  for(int it=0; it<3; it++){
    k_feats<<<4096,256,0,stream>>>(c_sel, cw, m_buf, q_hT, feats_bf);
    k_gemm_bf16<<<dim3(64,2),256,0,stream>>>(feats_bf, attw1_bf, 1824, b1pad, 1, h1, nullptr, 128);
    k_scores<<<1024,256,0,stream>>>(h1, att_w2, att_b2, scores);
    k_softmax_e<<<32,256,0,stream>>>(scores, len_c, c_sel, outp + 64000 + it*4096, e_buf);
    k_gru_cell<<<32,256,0,stream>>>(e_buf, 256, nullptr, 0, m_buf,
                                    mem_wihT, mem_whhT, mem_b_ih, mem_b_hh, m_buf);
  }

  // ---- answer module ----
  k_copy<<<32,256,0,stream>>>(m_buf, msq, 32*256);
  for(int it=0; it<2; it++){
    k_logits<<<250,256,0,stream>>>(msq, out_wT, out_b, ylin);
    k_softmax_o<<<32,256,0,stream>>>(ylin, ybuf);
    k_gru_cell<<<32,256,0,stream>>>(ybuf, 2000, q_hT, 256, msq,
                                    ans_wihT, ans_whhT, ans_b_ih, ans_b_hh, msq);
  }
  k_logits<<<250,256,0,stream>>>(msq, out_wT, out_b, ylin);
  k_softmax_o<<<32,256,0,stream>>>(ylin, outp);
}

// Round 7
// 3116.775 us; speedup vs baseline: 1.2291x; 1.2291x over previous
//
#include <hip/hip_runtime.h>
#include <hip/hip_bf16.h>
#include <cstdint>
#include <cstddef>

typedef short bf16x8 __attribute__((ext_vector_type(8)));
typedef float f32x4 __attribute__((ext_vector_type(4)));
typedef int   i32x4 __attribute__((ext_vector_type(4)));

#define DEV static __device__ __forceinline__

DEV unsigned short f2bf(float x){
  union{float f; unsigned int u;} v; v.f = x;
  unsigned int r = (v.u + 0x7FFFu + ((v.u>>16)&1u)) >> 16;
  return (unsigned short)r;
}
DEV float bf2f(unsigned short h){
  union{unsigned int u; float f;} v; v.u = ((unsigned int)h)<<16;
  return v.f;
}
// unpack bf16 half of a dword: hi=0 -> low u16, hi=1 -> high u16
DEV float bfsel(int dw, int hi){
  union{unsigned int u; float f;} v;
  v.u = hi ? ((unsigned int)dw & 0xFFFF0000u) : ((unsigned int)dw << 16);
  return v.f;
}
// fast gates: v_exp_f32 + v_rcp_f32
DEV float sigm_f(float x){ return __builtin_amdgcn_rcpf(1.0f + __expf(-x)); }
DEV float tanh_f(float x){ return 2.0f*__builtin_amdgcn_rcpf(1.0f + __expf(-2.0f*x)) - 1.0f; }

// ---------------- prep kernels ----------------
__global__ void k_f2bf(const float* __restrict__ src, unsigned short* __restrict__ dst, int n){
  int i = blockIdx.x*256 + threadIdx.x;
  if(i<n) dst[i] = f2bf(src[i]);
}

__global__ void k_transpose(const float* __restrict__ in, float* __restrict__ out, int R, int C){
  int i = blockIdx.x*256 + threadIdx.x;
  if(i < R*C){ int r = i/C, c = i - r*C; out[(size_t)c*R + r] = in[i]; }
}

__global__ void k_attw1(const float* __restrict__ w1, unsigned short* __restrict__ dst){
  int i = blockIdx.x*256 + threadIdx.x;  // 128*1824
  if(i < 128*1824){
    int r = i/1824, cc = i - r*1824;
    float v = (r<100 && cc<1794)? w1[r*1794 + cc] : 0.0f;
    dst[i] = f2bf(v);
  }
}

__global__ void k_attwT(const float* __restrict__ aw, unsigned short* __restrict__ dst){
  int i = blockIdx.x*256 + threadIdx.x;  // out[n*256+k] = aw[k*256+n]
  if(i<65536){ int n = i>>8, k = i&255; dst[i] = f2bf(aw[k*256 + n]); }
}

__global__ void k_b1pad(const float* __restrict__ b1, float* __restrict__ dst){
  int i = threadIdx.x; if(i<128) dst[i] = (i<100)? b1[i] : 0.0f;
}

__global__ void k_copy(const float* __restrict__ s, float* __restrict__ d, int n){
  int i = blockIdx.x*256+threadIdx.x; if(i<n) d[i]=s[i];
}

// ---------------- generic bf16 MFMA GEMM: C(M,N) = A(M,K) @ Bt(N,K)^T ----------------
__global__ __launch_bounds__(256) void k_gemm_bf16(
    const unsigned short* __restrict__ A, const unsigned short* __restrict__ Bt,
    int K, const float* __restrict__ bias, int act,
    float* __restrict__ outf, unsigned short* __restrict__ outbf, int ldc)
{
  int lane = threadIdx.x & 63, wave = threadIdx.x >> 6;
  int m_base = blockIdx.x*64 + (wave>>1)*32;
  int n_base = blockIdx.y*64 + (wave&1)*32;
  int cl = lane & 15, q4 = lane >> 4;
  f32x4 acc00={0.f,0.f,0.f,0.f}, acc01=acc00, acc10=acc00, acc11=acc00;
  const int kf_n = K >> 5;
  for(int kf=0; kf<kf_n; kf++){
    int ko = kf*32 + q4*8;
    bf16x8 a0 = *(const bf16x8*)(A + (size_t)(m_base+cl)*K + ko);
    bf16x8 a1 = *(const bf16x8*)(A + (size_t)(m_base+16+cl)*K + ko);
    bf16x8 b0 = *(const bf16x8*)(Bt + (size_t)(n_base+cl)*K + ko);
    bf16x8 b1 = *(const bf16x8*)(Bt + (size_t)(n_base+16+cl)*K + ko);
    acc00 = __builtin_amdgcn_mfma_f32_16x16x32_bf16(a0,b0,acc00,0,0,0);
    acc01 = __builtin_amdgcn_mfma_f32_16x16x32_bf16(a0,b1,acc01,0,0,0);
    acc10 = __builtin_amdgcn_mfma_f32_16x16x32_bf16(a1,b0,acc10,0,0,0);
    acc11 = __builtin_amdgcn_mfma_f32_16x16x32_bf16(a1,b1,acc11,0,0,0);
  }
  #pragma unroll
  for(int mt=0; mt<2; mt++){
    #pragma unroll
    for(int nt=0; nt<2; nt++){
      f32x4 av = (mt==0)? (nt==0?acc00:acc01) : (nt==0?acc10:acc11);
      int col = n_base + nt*16 + cl;
      float bv = bias? bias[col] : 0.0f;
      #pragma unroll
      for(int r=0;r<4;r++){
        int row = m_base + mt*16 + q4*4 + r;
        float v = av[r] + bv;
        if(act) v = tanh_f(v);
        if(outbf) outbf[(size_t)row*ldc + col] = f2bf(v);
        else      outf [(size_t)row*ldc + col] = v;
      }
    }
  }
}

// ---------------- gi GEMM with lane-packed scatter epilogue ----------------
// gi = x @ w_ih^T, bf16, biases folded: r/z get b_ih+b_hh, n gets b_ih only
// (b_hh_n must stay inside the r* term in the recurrence).
// Lane-packed: idx = L*24 + g*8 + s*4 + r, L = (((t*2 + blk)*8 + w)*64 + lane).
// A rows are b*steps + t (steps = 1<<ss). N = 768.
__global__ __launch_bounds__(256) void k_gemm_gi(
    const unsigned short* __restrict__ A, const unsigned short* __restrict__ Bt,
    const float* __restrict__ bih, const float* __restrict__ bhh,
    unsigned short* __restrict__ gi_out, int ss)
{
  int lane = threadIdx.x & 63, wave = threadIdx.x >> 6;
  int m_base = blockIdx.x*64 + (wave>>1)*32;
  int n_base = blockIdx.y*64 + (wave&1)*32;
  int cl = lane & 15, q4 = lane >> 4;
  f32x4 acc00={0.f,0.f,0.f,0.f}, acc01=acc00, acc10=acc00, acc11=acc00;
  for(int kf=0; kf<4; kf++){   // K = 128
    int ko = kf*32 + q4*8;
    bf16x8 a0 = *(const bf16x8*)(A + (size_t)(m_base+cl)*128 + ko);
    bf16x8 a1 = *(const bf16x8*)(A + (size_t)(m_base+16+cl)*128 + ko);
    bf16x8 b0 = *(const bf16x8*)(Bt + (size_t)(n_base+cl)*128 + ko);
    bf16x8 b1 = *(const bf16x8*)(Bt + (size_t)(n_base+16+cl)*128 + ko);
    acc00 = __builtin_amdgcn_mfma_f32_16x16x32_bf16(a0,b0,acc00,0,0,0);
    acc01 = __builtin_amdgcn_mfma_f32_16x16x32_bf16(a0,b1,acc01,0,0,0);
    acc10 = __builtin_amdgcn_mfma_f32_16x16x32_bf16(a1,b0,acc10,0,0,0);
    acc11 = __builtin_amdgcn_mfma_f32_16x16x32_bf16(a1,b1,acc11,0,0,0);
  }
  const int tmask = (1<<ss) - 1;
  #pragma unroll
  for(int mt=0; mt<2; mt++){
    #pragma unroll
    for(int nt=0; nt<2; nt++){
      f32x4 av = (mt==0)? (nt==0?acc00:acc01) : (nt==0?acc10:acc11);
      int col = n_base + nt*16 + cl;
      int g = col >> 8, rem = col & 255;
      int w = rem >> 5, s = (rem>>4)&1, cl2 = rem & 15;
      float badd = bih[col] + ((g<2)? bhh[col] : 0.0f);
      #pragma unroll
      for(int r=0;r<4;r++){
        int arow = m_base + mt*16 + q4*4 + r;
        int t = arow & tmask, b = arow >> ss;
        int blk = b >> 4, brow = b & 15;
        int lane2 = (brow>>2)*16 + cl2, rc = brow & 3;
        size_t idx = ((((size_t)t*2 + blk)*8 + w)*64 + lane2)*24 + g*8 + s*4 + rc;
        gi_out[idx] = f2bf(av[r] + badd);
      }
    }
  }
}

// ---------------- GRU recurrence ----------------
// 4 blocks (2 context, 2 query), 16 batch rows each, 8 waves.
// Gate-local tiling (wave w owns cols [32w,32w+32) of r/z/n); W register-resident.
// h double-buffered in LDS -> one __syncthreads per step (r4 skeleton; r5's
// lgkm-only barrier regressed and is NOT used).
// gi bf16 lane-packed 24/lane (r4 memory profile: 48 B/lane/step -- r6's f32 rz
// cost +17 MB FETCH = +775 us in this latency-starved 4-CU regime), r/z biases
// pre-folded. gi register-prefetched ONE STEP AHEAD: issued top of step t,
// drained by step t's __syncthreads, consumed phase B of t+1 -> full-step cover.
// c_out stored lane-packed (2x dwordx4) -- k_gather un-permutes.
__global__ __launch_bounds__(512,1) void k_gru_rec(
    const unsigned short* __restrict__ whh_c, const unsigned short* __restrict__ whh_q,
    const unsigned short* __restrict__ gi_c,  const unsigned short* __restrict__ gi_q,
    const float* __restrict__ bhh_c, const float* __restrict__ bhh_q,
    const float* __restrict__ h0_c,  const float* __restrict__ h0_q,
    float* __restrict__ c_hist, float* __restrict__ q_hT)
{
  __shared__ unsigned short hb0[16*264];   // double-buffered h (row stride 264 u16)
  __shared__ unsigned short hb1[16*264];

  const int blk = blockIdx.x;
  const bool isq = blk >= 2;
  const int cls = isq? blk-2 : blk;        // block index within class (0/1)
  const int b0 = cls * 16;
  const unsigned short* W  = isq? whh_q : whh_c;
  const unsigned short* GI = isq? gi_q  : gi_c;
  const float* bhh = isq? bhh_q : bhh_c;
  const float* h0  = isq? h0_q  : h0_c;
  const int steps  = isq? 32 : 1024;

  const int tid = threadIdx.x;
  const int lane = tid & 63, wave = tid >> 6;
  const int cl = lane & 15, q4 = lane >> 4;

  // B-fragments: [gate][subtile][kfrag], col = g*256 + wave*32 + s*16 + cl
  bf16x8 Bf[3][2][8];
  #pragma unroll
  for(int g=0; g<3; g++)
    #pragma unroll
    for(int s=0; s<2; s++){
      const unsigned short* wrow = W + (size_t)(g*256 + wave*32 + s*16 + cl)*256;
      #pragma unroll
      for(int kf=0; kf<8; kf++)
        Bf[g][s][kf] = *(const bf16x8*)(wrow + kf*32 + q4*8);
    }

  // n-gate hidden bias for owned cols (r/z biases folded into gi)
  float bN[2];
  #pragma unroll
  for(int s=0; s<2; s++){
    const int col = wave*32 + s*16 + cl;
    bN[s] = bhh[512+col];
  }

  // h in registers: lane owns (row=q4*4+r, col=wave*32+s*16+cl), hreg[s][r]
  f32x4 hreg[2];
  #pragma unroll
  for(int s=0; s<2; s++){
    const int col = wave*32 + s*16 + cl;
    #pragma unroll
    for(int r=0; r<4; r++){
      const int row = q4*4 + r;
      float v = h0[(size_t)(b0+row)*256 + col];
      hreg[s][r] = v;
      hb0[row*264 + col] = f2bf(v);
    }
  }
  __syncthreads();

  unsigned short* hb_rd = hb0;
  unsigned short* hb_wr = hb1;

  // per-lane gi base; lane-packed c_hist base
  const unsigned short* gi_lane = GI + (((size_t)cls*8 + wave)*64 + lane)*24;
  const size_t gi_tstride = (size_t)2*8*64*24;           // u16 per t
  float* ch_lane = c_hist + (((size_t)cls*8 + wave)*64 + lane)*8;
  const size_t ch_tstride = (size_t)2*8*64*8;            // f32 per t (=8192)

  // gi(0) into current regs
  i32x4 Gc0 = *(const i32x4*)(gi_lane);
  i32x4 Gc1 = *(const i32x4*)(gi_lane + 8);
  i32x4 Gc2 = *(const i32x4*)(gi_lane + 16);

  for(int t=0; t<steps; t++){
    // prefetch gi(t+1): issued now, drained by this step's barrier, consumed next step
    const unsigned short* gpn = gi_lane + (size_t)((t+1<steps)? t+1 : t)*gi_tstride;
    i32x4 Gn0 = *(const i32x4*)(gpn);
    i32x4 Gn1 = *(const i32x4*)(gpn + 8);
    i32x4 Gn2 = *(const i32x4*)(gpn + 16);

    // deferred lane-packed c_hist store of h(t-1): overlaps with MFMA phase
    if(!isq && t>0){
      float* cp = ch_lane + (size_t)(t-1)*ch_tstride;
      *(f32x4*)cp       = hreg[0];
      *(f32x4*)(cp + 4) = hreg[1];
    }

    // phase A: gates = h @ W^T  (48 MFMAs/wave)
    f32x4 acc[3][2];
    #pragma unroll
    for(int g=0; g<3; g++)
      #pragma unroll
      for(int s=0; s<2; s++){ f32x4 z={0.f,0.f,0.f,0.f}; acc[g][s]=z; }
    #pragma unroll
    for(int kf=0; kf<8; kf++){
      bf16x8 a = *(const bf16x8*)&hb_rd[cl*264 + kf*32 + q4*8];
      #pragma unroll
      for(int g=0; g<3; g++)
        #pragma unroll
        for(int s=0; s<2; s++)
          acc[g][s] = __builtin_amdgcn_mfma_f32_16x16x32_bf16(a, Bf[g][s][kf], acc[g][s], 0,0,0);
    }

    // phase B: in-register GRU update (writes OTHER h buffer)
    #pragma unroll
    for(int s=0; s<2; s++){
      const int col = wave*32 + s*16 + cl;
      float x4[4];
      #pragma unroll
      for(int r=0; r<4; r++){
        const int k = s*4 + r;
        float rr = sigm_f(bfsel(Gc0[k>>1], k&1) + acc[0][s][r]);
        float zz = sigm_f(bfsel(Gc1[k>>1], k&1) + acc[1][s][r]);
        float nn = tanh_f(bfsel(Gc2[k>>1], k&1) + rr*(acc[2][s][r] + bN[s]));
        float x  = nn + zz*(hreg[s][r] - nn);
        hreg[s][r] = x;
        x4[r] = x;
      }
      // packed bf16 writeback: v_cvt_pk_bf16_f32 (2 values/instr)
      #pragma unroll
      for(int p=0; p<2; p++){
        __hip_bfloat162 bb = __float22bfloat162_rn(make_float2(x4[2*p], x4[2*p+1]));
        union{ __hip_bfloat162 b; unsigned int u; } cvt; cvt.b = bb;
        const int row = q4*4 + 2*p;
        hb_wr[row*264 + col]     = (unsigned short)(cvt.u & 0xFFFFu);
        hb_wr[(row+1)*264 + col] = (unsigned short)(cvt.u >> 16);
      }
    }
    __syncthreads();   // hb_wr complete; gi(t+1) drained -> next step stall-free
    unsigned short* tmp = hb_rd; hb_rd = hb_wr; hb_wr = tmp;
    Gc0 = Gn0; Gc1 = Gn1; Gc2 = Gn2;
  }

  // final stores from hreg
  if(!isq){
    float* cp = ch_lane + (size_t)(steps-1)*ch_tstride;
    *(f32x4*)cp       = hreg[0];
    *(f32x4*)(cp + 4) = hreg[1];
  } else {
    #pragma unroll
    for(int s=0; s<2; s++){
      const int col = wave*32 + s*16 + cl;
      #pragma unroll
      for(int r=0; r<4; r++)
        q_hT[(size_t)(b0+q4*4+r)*256 + col] = hreg[s][r];
    }
  }
}

// ---------------- attention helpers ----------------
// c_hist is lane-packed: addr(t,b,col) = t*8192 + cls*4096 + w*512 + lane*8 + j
// with cls=b>>4, brow=b&15, q4=brow>>2, rI=brow&3, w=col>>5, sI=(col>>4)&1,
// cl=col&15, lane=q4*16+cl, j=sI*4+rI.
__global__ void k_gather(const float* __restrict__ c_hist, const int* __restrict__ c_index,
                         float* __restrict__ c_sel, unsigned short* __restrict__ c_sel_bf){
  int row = blockIdx.x;                 // 0..4095 = b*128+s
  int b = row >> 7, s = row & 127;
  int idx = c_index[b*128 + s];
  int col = threadIdx.x;
  int cls = b >> 4, brow = b & 15;
  int q4 = brow >> 2, rI = brow & 3;
  int w = col >> 5, sI = (col>>4)&1, cl = col & 15;
  size_t addr = (size_t)idx*8192 + (size_t)cls*4096 + w*512 + (q4*16+cl)*8 + sI*4 + rI;
  float v = c_hist[addr];
  c_sel   [(size_t)row*256 + col] = v;
  c_sel_bf[(size_t)row*256 + col] = f2bf(v);
}

__global__ void k_feats(const float* __restrict__ c_sel, const float* __restrict__ cw,
                        const float* __restrict__ m_, const float* __restrict__ qh,
                        unsigned short* __restrict__ feats){
  int row = blockIdx.x, tid = threadIdx.x;
  int b = row >> 7;
  float cs  = c_sel[(size_t)row*256 + tid];
  float mj  = m_[b*256 + tid];
  float qj  = qh[b*256 + tid];
  float cwj = cw[(size_t)row*256 + tid];
  float dq = cwj*qj, dm = cwj*mj;
  #pragma unroll
  for(int o=32;o>0;o>>=1){ dq += __shfl_down(dq,o); dm += __shfl_down(dm,o); }
  __shared__ float rq[4], rm[4];
  int lane = tid&63, wave=tid>>6;
  if(lane==0){ rq[wave]=dq; rm[wave]=dm; }
  __syncthreads();
  unsigned short* fr = feats + (size_t)row*1824;
  fr[tid]      = f2bf(cs);
  fr[256+tid]  = f2bf(mj);
  fr[512+tid]  = f2bf(qj);
  fr[768+tid]  = f2bf(cs*qj);
  fr[1024+tid] = f2bf(cs*mj);
  fr[1280+tid] = f2bf(fabsf(cs-qj));
  fr[1536+tid] = f2bf(fabsf(cs-mj));
  if(tid==0){
    float DQ = rq[0]+rq[1]+rq[2]+rq[3];
    float DM = rm[0]+rm[1]+rm[2]+rm[3];
    fr[1792]=f2bf(DQ); fr[1793]=f2bf(DM);
  }
  if(tid<30) fr[1794+tid]=0;   // zero K-pad
}

__global__ void k_scores(const float* __restrict__ h1, const float* __restrict__ w2,
                         const float* __restrict__ b2, float* __restrict__ scores){
  int row = blockIdx.x*4 + (threadIdx.x>>6);
  int lane = threadIdx.x & 63;
  float v = 0.0f;
  if(lane < 100)    v += h1[(size_t)row*128 + lane]*w2[lane];
  if(lane+64 < 100) v += h1[(size_t)row*128 + lane+64]*w2[lane+64];
  #pragma unroll
  for(int o=32;o>0;o>>=1) v += __shfl_down(v,o);
  if(lane==0) scores[row] = v + b2[0];
}

__global__ void k_softmax_e(const float* __restrict__ scores, const int* __restrict__ len_c,
                            const float* __restrict__ c_sel, float* __restrict__ out_att,
                            float* __restrict__ e){
  __shared__ float red[256];
  __shared__ float p[128];
  int b = blockIdx.x, tid = threadIdx.x;
  int L = len_c[b];
  float s = -1e30f;
  if(tid<128 && tid<L) s = scores[b*128+tid];
  red[tid]=s; __syncthreads();
  for(int o=128;o>0;o>>=1){ if(tid<o) red[tid]=fmaxf(red[tid],red[tid+o]); __syncthreads(); }
  float mx = red[0]; __syncthreads();
  float ex = (tid<128 && tid<L)? __expf(s-mx) : 0.0f;
  red[tid]=ex; __syncthreads();
  for(int o=128;o>0;o>>=1){ if(tid<o) red[tid]+=red[tid+o]; __syncthreads(); }
  float inv = 1.0f/red[0];
  if(tid<128){ float pv = ex*inv; p[tid]=pv; out_att[b*128+tid]=pv; }
  __syncthreads();
  float acc = 0.0f;
  for(int si=0; si<128; si++) acc += p[si]*c_sel[((size_t)b*128+si)*256 + tid];
  e[b*256+tid] = acc;
}

// ---------------- small fp32 GRU cell (mem/ans updates), x = [x1 || x2] ----------------
__global__ void k_gru_cell(const float* __restrict__ x1, int len1,
                           const float* __restrict__ x2, int len2,
                           const float* __restrict__ hprev,
                           const float* __restrict__ wihT, const float* __restrict__ whhT,
                           const float* __restrict__ bih, const float* __restrict__ bhh,
                           float* __restrict__ hout){
  __shared__ float xs[2304];
  __shared__ float hs[256];
  int m = blockIdx.x, tid = threadIdx.x;
  int Kx = len1 + len2;
  for(int i=tid;i<len1;i+=256) xs[i] = x1[(size_t)m*len1 + i];
  for(int i=tid;i<len2;i+=256) xs[len1+i] = x2[(size_t)m*len2 + i];
  hs[tid] = hprev[m*256 + tid];
  __syncthreads();
  float ar=0, az=0, an=0;
  for(int k=0;k<Kx;k++){
    float xv = xs[k];
    const float* wr = wihT + (size_t)k*768;
    ar += xv*wr[tid]; az += xv*wr[256+tid]; an += xv*wr[512+tid];
  }
  float gr=0, gz=0, gn=0;
  for(int k=0;k<256;k++){
    float hv = hs[k];
    const float* wr = whhT + (size_t)k*768;
    gr += hv*wr[tid]; gz += hv*wr[256+tid]; gn += hv*wr[512+tid];
  }
  float rr = sigm_f(ar + bih[tid]     + gr + bhh[tid]);
  float zz = sigm_f(az + bih[256+tid] + gz + bhh[256+tid]);
  float nn = tanh_f(an + bih[512+tid] + rr*(gn + bhh[512+tid]));
  hout[m*256+tid] = (1.0f-zz)*nn + zz*hs[tid];
}

// ---------------- answer head ----------------
__global__ void k_logits(const float* __restrict__ msq, const float* __restrict__ out_wT,
                         const float* __restrict__ out_b, float* __restrict__ ylin){
  int i = blockIdx.x*256 + threadIdx.x;
  if(i >= 32*2000) return;
  int mrow = i/2000, n = i - mrow*2000;
  float acc = out_b[n];
  const float* mr = msq + mrow*256;
  for(int k=0;k<256;k++) acc += mr[k]*out_wT[(size_t)k*2000 + n];
  ylin[i] = acc;
}

__global__ void k_softmax_o(const float* __restrict__ x, float* __restrict__ y){
  __shared__ float red[256];
  int b = blockIdx.x, tid = threadIdx.x;
  const float* xr = x + (size_t)b*2000;
  float mx = -1e30f;
  for(int i=tid;i<2000;i+=256) mx = fmaxf(mx, xr[i]);
  red[tid]=mx; __syncthreads();
  for(int o=128;o>0;o>>=1){ if(tid<o) red[tid]=fmaxf(red[tid],red[tid+o]); __syncthreads(); }
  mx = red[0]; __syncthreads();
  float sum=0.0f;
  for(int i=tid;i<2000;i+=256) sum += __expf(xr[i]-mx);
  red[tid]=sum; __syncthreads();
  for(int o=128;o>0;o>>=1){ if(tid<o) red[tid]+=red[tid+o]; __syncthreads(); }
  float inv = 1.0f/red[0];
  for(int i=tid;i<2000;i+=256) y[(size_t)b*2000+i] = __expf(xr[i]-mx)*inv;
}

// ---------------- launch ----------------
extern "C" void kernel_launch(void* const* d_in, const int* in_sizes, int n_in,
                              void* d_out, int out_size, void* d_ws, size_t ws_size,
                              hipStream_t stream)
{
  const float* c        = (const float*)d_in[0];
  const float* q        = (const float*)d_in[1];
  const float* i_state  = (const float*)d_in[2];
  const float* q_state  = (const float*)d_in[3];
  const float* in_w_ih  = (const float*)d_in[4];
  const float* in_w_hh  = (const float*)d_in[5];
  const float* in_b_ih  = (const float*)d_in[6];
  const float* in_b_hh  = (const float*)d_in[7];
  const float* qe_w_ih  = (const float*)d_in[8];
  const float* qe_w_hh  = (const float*)d_in[9];
  const float* qe_b_ih  = (const float*)d_in[10];
  const float* qe_b_hh  = (const float*)d_in[11];
  const float* att_weight = (const float*)d_in[12];
  const float* att_w1   = (const float*)d_in[13];
  const float* att_b1   = (const float*)d_in[14];
  const float* att_w2   = (const float*)d_in[15];
  const float* att_b2   = (const float*)d_in[16];
  const float* mem_w_ih = (const float*)d_in[17];
  const float* mem_w_hh = (const float*)d_in[18];
  const float* mem_b_ih = (const float*)d_in[19];
  const float* mem_b_hh = (const float*)d_in[20];
  const float* out_w    = (const float*)d_in[21];
  const float* out_b    = (const float*)d_in[22];
  const float* ans_w_ih = (const float*)d_in[23];
  const float* ans_w_hh = (const float*)d_in[24];
  const float* ans_b_ih = (const float*)d_in[25];
  const float* ans_b_hh = (const float*)d_in[26];
  const int*   c_index  = (const int*)d_in[27];
  const int*   len_c    = (const int*)d_in[28];
  float* outp = (float*)d_out;   // [0,64000) y ; [64000,76288) att (3,32,128)

  char* wp = (char*)d_ws;
  auto take = [&](size_t nbytes)->char*{
    char* p = wp; wp += (nbytes + 255) & ~(size_t)255; return p;
  };
  unsigned short* c_bf      = (unsigned short*)take((size_t)32*1024*128*2);
  unsigned short* q_bf      = (unsigned short*)take((size_t)32*32*128*2);
  unsigned short* wih_in_bf = (unsigned short*)take(768*128*2);
  unsigned short* wih_qe_bf = (unsigned short*)take(768*128*2);
  unsigned short* whh_in_bf = (unsigned short*)take(768*256*2);
  unsigned short* whh_qe_bf = (unsigned short*)take(768*256*2);
  unsigned short* attwT_bf  = (unsigned short*)take(256*256*2);
  unsigned short* attw1_bf  = (unsigned short*)take(128*1824*2);
  float* b1pad              = (float*)take(128*4);
  float* out_wT             = (float*)take((size_t)256*2000*4);
  float* mem_wihT           = (float*)take(256*768*4);
  float* mem_whhT           = (float*)take(256*768*4);
  float* ans_wihT           = (float*)take((size_t)2256*768*4);
  float* ans_whhT           = (float*)take(256*768*4);
  unsigned short* gi_c_bf   = (unsigned short*)take((size_t)32768*768*2);  // lane-packed bf16
  unsigned short* gi_q_bf   = (unsigned short*)take((size_t)1024*768*2);   // lane-packed bf16
  float* c_hist             = (float*)take((size_t)1024*8192*4);           // lane-packed h history
  float* q_hT               = (float*)take(32*256*4);
  float* c_sel              = (float*)take((size_t)4096*256*4);
  unsigned short* c_sel_bf  = (unsigned short*)take((size_t)4096*256*2);
  float* cw                 = (float*)take((size_t)4096*256*4);
  unsigned short* feats_bf  = (unsigned short*)take((size_t)4096*1824*2);
  float* h1                 = (float*)take((size_t)4096*128*4);
  float* scores             = (float*)take(4096*4);
  float* e_buf              = (float*)take(32*256*4);
  float* m_buf              = (float*)take(32*256*4);
  float* msq                = (float*)take(32*256*4);
  float* ylin               = (float*)take((size_t)32*2000*4);
  float* ybuf               = (float*)take((size_t)32*2000*4);

  // ---- prep / conversions ----
  k_f2bf<<<16384,256,0,stream>>>(c, c_bf, 32*1024*128);
  k_f2bf<<<512,256,0,stream>>>(q, q_bf, 32*32*128);
  k_f2bf<<<384,256,0,stream>>>(in_w_ih, wih_in_bf, 768*128);
  k_f2bf<<<384,256,0,stream>>>(qe_w_ih, wih_qe_bf, 768*128);
  k_f2bf<<<768,256,0,stream>>>(in_w_hh, whh_in_bf, 768*256);
  k_f2bf<<<768,256,0,stream>>>(qe_w_hh, whh_qe_bf, 768*256);
  k_attwT<<<256,256,0,stream>>>(att_weight, attwT_bf);
  k_attw1<<<912,256,0,stream>>>(att_w1, attw1_bf);
  k_b1pad<<<1,128,0,stream>>>(att_b1, b1pad);
  k_transpose<<<2000,256,0,stream>>>(out_w, out_wT, 2000, 256);
  k_transpose<<<768,256,0,stream>>>(mem_w_ih, mem_wihT, 768, 256);
  k_transpose<<<768,256,0,stream>>>(mem_w_hh, mem_whhT, 768, 256);
  k_transpose<<<6768,256,0,stream>>>(ans_w_ih, ans_wihT, 768, 2256);
  k_transpose<<<768,256,0,stream>>>(ans_w_hh, ans_whhT, 768, 256);

  // ---- time-parallel input projections, lane-packed bf16 + bias-folded ----
  k_gemm_gi<<<dim3(512,12),256,0,stream>>>(c_bf, wih_in_bf, in_b_ih, in_b_hh, gi_c_bf, 10);
  k_gemm_gi<<<dim3(16,12),256,0,stream>>>(q_bf, wih_qe_bf, qe_b_ih, qe_b_hh, gi_q_bf, 5);

  // ---- sequential GRU recurrences (context 1024 steps + query 32 steps) ----
  k_gru_rec<<<4,512,0,stream>>>(whh_in_bf, whh_qe_bf, gi_c_bf, gi_q_bf,
                                in_b_hh, qe_b_hh, i_state, q_state, c_hist, q_hT);

  // ---- attention setup ----
  k_gather<<<4096,256,0,stream>>>(c_hist, c_index, c_sel, c_sel_bf);
  k_gemm_bf16<<<dim3(64,4),256,0,stream>>>(c_sel_bf, attwT_bf, 256, nullptr, 0, cw, nullptr, 256);
  k_copy<<<32,256,0,stream>>>(q_hT, m_buf, 32*256);

  // ---- 3 episodic memory iterations ----
  for(int it=0; it<3; it++){
    k_feats<<<4096,256,0,stream>>>(c_sel, cw, m_buf, q_hT, feats_bf);
    k_gemm_bf16<<<dim3(64,2),256,0,stream>>>(feats_bf, attw1_bf, 1824, b1pad, 1, h1, nullptr, 128);
    k_scores<<<1024,256,0,stream>>>(h1, att_w2, att_b2, scores);
    k_softmax_e<<<32,256,0,stream>>>(scores, len_c, c_sel, outp + 64000 + it*4096, e_buf);
    k_gru_cell<<<32,256,0,stream>>>(e_buf, 256, nullptr, 0, m_buf,
                                    mem_wihT, mem_whhT, mem_b_ih, mem_b_hh, m_buf);
  }

  // ---- answer module ----
  k_copy<<<32,256,0,stream>>>(m_buf, msq, 32*256);
  for(int it=0; it<2; it++){
    k_logits<<<250,256,0,stream>>>(msq, out_wT, out_b, ylin);
    k_softmax_o<<<32,256,0,stream>>>(ylin, ybuf);
    k_gru_cell<<<32,256,0,stream>>>(ybuf, 2000, q_hT, 256, msq,
                                    ans_wihT, ans_whhT, ans_b_ih, ans_b_hh, msq);
  }
  k_logits<<<250,256,0,stream>>>(msq, out_wT, out_b, ylin);
  k_softmax_o<<<32,256,0,stream>>>(ylin, outp);
}